// Round 9
// baseline (163.552 us; speedup 1.0000x reference)
//
#include <hip/hip_runtime.h>
#include <hip/hip_fp16.h>

#define Bsz 256
#define Nn  1152
#define Kk  10
#define NT  384      // 6 waves/block
#define NW  6

#define W_ELEMS (Kk*Nn*128)     // 1474560
#define U_ELEMS (Bsz*Nn*8)      // 2359296

typedef _Float16 hf2_t __attribute__((ext_vector_type(2)));

static __device__ __forceinline__ unsigned pkh2(float x, float y) {
    __half2 h = __floats2half2_rn(x, y);
    return *reinterpret_cast<unsigned*>(&h);
}
// v_dot2_f32_f16: c += a.lo*b.lo + a.hi*b.hi (f32 accumulate, 1 inst)
static __device__ __forceinline__ float fdot2u(unsigned a, unsigned b, float c) {
    union { unsigned u; hf2_t h; } A, B;
    A.u = a; B.u = b;
    return __builtin_amdgcn_fdot2(A.h, B.h, c, false);
}

#define PERM_LO 0x01000504u   // perm(a,b,LO) = half2(lo = lo16(a), hi = lo16(b))
#define PERM_HI 0x03020706u   // perm(a,b,HI) = half2(lo = hi16(a), hi = hi16(b))
#define ONE2    0x3C003C00u   // half2(1, 1)

// Simple elementwise fp32->fp16 of W then u (8 elems/thread), layouts unchanged.
// (Round-2/3/8 verified; W layout stays i-major [k][n][8i][16o].)
__global__ void cvt_kernel(const float* __restrict__ W, const float* __restrict__ u,
                           __half2* __restrict__ Wh, __half2* __restrict__ uh) {
    const int idx = blockIdx.x * blockDim.x + threadIdx.x;
    const int wg = W_ELEMS / 8;            // 184320
    const float4* p;
    __half2* o;
    if (idx < wg) {
        p = (const float4*)W + (size_t)idx * 2;
        o = Wh + (size_t)idx * 4;
    } else {
        const int j = idx - wg;            // < 294912
        p = (const float4*)u + (size_t)j * 2;
        o = uh + (size_t)j * 4;
    }
    const float4 a = p[0], b = p[1];
    o[0] = __floats2half2_rn(a.x, a.y);
    o[1] = __floats2half2_rn(a.z, a.w);
    o[2] = __floats2half2_rn(b.x, b.y);
    o[3] = __floats2half2_rn(b.z, b.w);
}

// One block per (b, k). Lane (oh = lane&1, pr = lane>>1) of wave w owns rows
// n = 192*rr + 32*w + pr (rr=0..5) and o in [8*oh, 8*oh+8) — u_hat held in 24
// packed-half2 VGPRs. Routing is fully register/shfl-based:
//   a-scan  : 4 dot2/row + partner shfl_xor(1)   (no LDS)
//   softmax : per-wave max in regs; c[6] in regs (no LDS)
//   s-scan  : in-register row-pair perm+dot2, shfl-reduce over pr (offsets 2..32,
//             oh groups stay separate so d is not double-counted)
// LDS = redS exchange only (960 B). Cross-wave rescale exp(m_w - M) at finalize
// (round-7/8 verified). 3 barriers total. All arrays statically indexed.
template<bool HALF>
__global__ __launch_bounds__(NT, 6)
void digitcaps_kernel(const float* __restrict__ u32, const float* __restrict__ W32,
                      const __half* __restrict__ uh, const __half* __restrict__ Wh,
                      float* __restrict__ out)
{
    const int t    = threadIdx.x;
    const int lane = t & 63;
    const int wav  = t >> 6;
    const int oh   = lane & 1;
    const int pr   = lane >> 1;          // 0..31
    const int b    = blockIdx.x;         // 0..255
    const int k    = blockIdx.y;         // 0..9

    __shared__ float redS[2][NW][20];    // [buf][wav][s0..15, d, m_w, pad2] = 960 B

    unsigned uh_r[6][4];                 // [rr][jj]: half2(uh[n][8oh+2jj], uh[n][8oh+2jj+1])

    // ---------------- Phase 1: u_hat = u . W (round-8 verified body -> regs) ----------------
    #pragma unroll
    for (int rr = 0; rr < 6; ++rr) {
        const int n = 192 * rr + 32 * wav + pr;
        float a0[8];
        #pragma unroll
        for (int o = 0; o < 8; ++o) a0[o] = 0.f;
        if (HALF) {
            const uint4 uq = *(const uint4*)(uh + ((size_t)b * Nn + n) * 8);
            const unsigned uw[4] = {uq.x, uq.y, uq.z, uq.w};
            const __half* wbase = Wh + ((size_t)(k * Nn + n)) * 128 + oh * 8;
            #pragma unroll
            for (int p = 0; p < 4; ++p) {
                const uint4 qa = *(const uint4*)(wbase + (2 * p    ) * 16);
                const uint4 qb = *(const uint4*)(wbase + (2 * p + 1) * 16);
                const unsigned aw[4] = {qa.x, qa.y, qa.z, qa.w};
                const unsigned bw[4] = {qb.x, qb.y, qb.z, qb.w};
                #pragma unroll
                for (int jj = 0; jj < 4; ++jj) {
                    const unsigned wl  = __builtin_amdgcn_perm(aw[jj], bw[jj], PERM_LO);
                    const unsigned wh2 = __builtin_amdgcn_perm(aw[jj], bw[jj], PERM_HI);
                    a0[2*jj]   = fdot2u(wl,  uw[p], a0[2*jj]);
                    a0[2*jj+1] = fdot2u(wh2, uw[p], a0[2*jj+1]);
                }
            }
        } else {
            float ua[8];
            const float4* up = (const float4*)(u32 + ((size_t)b * Nn + n) * 8);
            const float4 x0 = up[0], x1 = up[1];
            ua[0]=x0.x; ua[1]=x0.y; ua[2]=x0.z; ua[3]=x0.w;
            ua[4]=x1.x; ua[5]=x1.y; ua[6]=x1.z; ua[7]=x1.w;
            #pragma unroll
            for (int i = 0; i < 8; ++i) {
                const float4* wp = (const float4*)(W32 + ((size_t)k * Nn + n) * 128) + oh * 2 + i * 4;
                const float4 w0 = wp[0], w1 = wp[1];
                float wv[8];
                wv[0]=w0.x; wv[1]=w0.y; wv[2]=w0.z; wv[3]=w0.w;
                wv[4]=w1.x; wv[5]=w1.y; wv[6]=w1.z; wv[7]=w1.w;
                const float x = ua[i];
                #pragma unroll
                for (int o = 0; o < 8; ++o) a0[o] += x * wv[o];
            }
        }
        #pragma unroll
        for (int jj = 0; jj < 4; ++jj)
            uh_r[rr][jj] = pkh2(a0[2*jj], a0[2*jj+1]);
    }

    // ---------------- Phase 2: routing (register/shfl; 1 barrier per iter) ----------------
    float lg[6] = {0.f, 0.f, 0.f, 0.f, 0.f, 0.f};
    unsigned vh[8];

    #pragma unroll
    for (int it = 0; it < 3; ++it) {
        float m_w = 0.f;
        float c[6];
        if (it > 0) {
            // ---- a-scan: own 8 o via dot2, partner half via shfl_xor(1) ----
            #pragma unroll
            for (int rr = 0; rr < 6; ++rr) {
                float acc = 0.f;
                #pragma unroll
                for (int jj = 0; jj < 4; ++jj)
                    acc = fdot2u(uh_r[rr][jj], vh[4 * oh + jj], acc);
                lg[rr] += acc + __shfl_xor(acc, 1);
            }
            // ---- per-wave max (regs + shfl only) ----
            float m = lg[0];
            #pragma unroll
            for (int rr = 1; rr < 6; ++rr) m = fmaxf(m, lg[rr]);
            #pragma unroll
            for (int off = 1; off <= 32; off <<= 1)
                m = fmaxf(m, __shfl_xor(m, off));
            m_w = m;
            // ---- c in registers (e <= 1; oh pair computes identical values) ----
            #pragma unroll
            for (int rr = 0; rr < 6; ++rr) c[rr] = __expf(lg[rr] - m_w);
        } else {
            #pragma unroll
            for (int rr = 0; rr < 6; ++rr) c[rr] = 1.f;
        }

        // ---- s-scan: in-register row-pair perm + dot2 ----
        float sp[8] = {0.f, 0.f, 0.f, 0.f, 0.f, 0.f, 0.f, 0.f};
        float dp = 0.f;
        #pragma unroll
        for (int q = 0; q < 3; ++q) {
            const unsigned cp = pkh2(c[2*q], c[2*q+1]);    // (c[n_2q] lo, c[n_2q+1] hi)
            dp = fdot2u(cp, ONE2, dp);
            #pragma unroll
            for (int jj = 0; jj < 4; ++jj) {
                // px = (uh[n_2q][2jj] lo, uh[n_2q+1][2jj] hi) — round-3-verified pairing
                const unsigned px = __builtin_amdgcn_perm(uh_r[2*q][jj], uh_r[2*q+1][jj], PERM_LO);
                const unsigned py = __builtin_amdgcn_perm(uh_r[2*q][jj], uh_r[2*q+1][jj], PERM_HI);
                sp[2*jj]   = fdot2u(px, cp, sp[2*jj]);
                sp[2*jj+1] = fdot2u(py, cp, sp[2*jj+1]);
            }
        }
        // reduce over pr lanes; offsets 2..32 keep oh groups separate (no d double-count)
        #pragma unroll
        for (int off = 2; off <= 32; off <<= 1) {
            #pragma unroll
            for (int e = 0; e < 8; ++e) sp[e] += __shfl_xor(sp[e], off);
            dp += __shfl_xor(dp, off);
        }
        const int buf = it & 1;
        if (lane < 2) {      // lane == oh here; lane0 -> s[0..7], lane1 -> s[8..15]
            float2* dst = (float2*)&redS[buf][wav][8 * lane];
            dst[0] = make_float2(sp[0], sp[1]);
            dst[1] = make_float2(sp[2], sp[3]);
            dst[2] = make_float2(sp[4], sp[5]);
            dst[3] = make_float2(sp[6], sp[7]);
        }
        if (lane == 0)
            *(float2*)&redS[buf][wav][16] = make_float2(dp, m_w);
        __syncthreads();                               // the ONLY barrier per iter

        // ---- finalize: cross-wave rescale + squash (round-8 verified) ----
        if (it < 2 || wav == 0) {
            const int o = lane & 15;
            float M = redS[buf][0][17];
            #pragma unroll
            for (int w = 1; w < NW; ++w) M = fmaxf(M, redS[buf][w][17]);
            float s = 0.f, d = 0.f;
            #pragma unroll
            for (int w = 0; w < NW; ++w) {
                const float2 dm = *(const float2*)&redS[buf][w][16];
                const float sc = (it == 0) ? 1.f : __expf(dm.y - M);
                s += sc * redS[buf][w][o];
                d += sc * dm.x;
            }
            s /= d;
            float s2 = s * s;
            #pragma unroll
            for (int off = 1; off <= 8; off <<= 1) s2 += __shfl_xor(s2, off);
            const float scale = (s2 / (1.f + s2)) * rsqrtf(fmaxf(s2, 1e-30f));
            const float v = s * scale;
            if (it == 2) {
                if (wav == 0 && lane < 16)
                    out[((size_t)k * Bsz + b) * 16 + lane] = v;
            } else {
                #pragma unroll
                for (int j = 0; j < 8; ++j)
                    vh[j] = pkh2(__shfl(v, 2*j), __shfl(v, 2*j + 1));
            }
        }
    }
}

extern "C" void kernel_launch(void* const* d_in, const int* in_sizes, int n_in,
                              void* d_out, int out_size, void* d_ws, size_t ws_size,
                              hipStream_t stream) {
    const float* u = (const float*)d_in[0];
    const float* W = (const float*)d_in[1];
    float* out = (float*)d_out;
    const size_t need = (size_t)(W_ELEMS + U_ELEMS) * sizeof(__half);
    if (ws_size >= need) {
        __half* Wh = (__half*)d_ws;
        __half* uh = (__half*)((char*)d_ws + (size_t)W_ELEMS * sizeof(__half));
        cvt_kernel<<<dim3((W_ELEMS + U_ELEMS) / 8 / 256), dim3(256), 0, stream>>>(
            W, u, (__half2*)Wh, (__half2*)uh);
        digitcaps_kernel<true><<<dim3(256, 10), dim3(NT), 0, stream>>>(
            nullptr, nullptr, uh, Wh, out);
    } else {
        digitcaps_kernel<false><<<dim3(256, 10), dim3(NT), 0, stream>>>(
            u, W, nullptr, nullptr, out);
    }
}

// Round 11
// 145.542 us; speedup vs baseline: 1.1237x; 1.1237x over previous
//
#include <hip/hip_runtime.h>
#include <hip/hip_fp16.h>

#define Bsz 256
#define Nn  1152
#define Kk  10
#define NT  384      // 6 waves/block
#define NW  6

#define W_ELEMS (Kk*Nn*128)     // 1474560
#define U_ELEMS (Bsz*Nn*8)      // 2359296

typedef _Float16 hf2_t __attribute__((ext_vector_type(2)));

static __device__ __forceinline__ unsigned pkh2(float x, float y) {
    __half2 h = __floats2half2_rn(x, y);
    return *reinterpret_cast<unsigned*>(&h);
}
// v_dot2_f32_f16: c += a.lo*b.lo + a.hi*b.hi (f32 accumulate, 1 inst)
static __device__ __forceinline__ float fdot2u(unsigned a, unsigned b, float c) {
    union { unsigned u; hf2_t h; } A, B;
    A.u = a; B.u = b;
    return __builtin_amdgcn_fdot2(A.h, B.h, c, false);
}

#define PERM_LO 0x01000504u   // perm(a,b,LO) = half2(lo = lo16(a), hi = lo16(b))
#define PERM_HI 0x03020706u   // perm(a,b,HI) = half2(lo = hi16(a), hi = hi16(b))
#define ONE2    0x3C003C00u   // half2(1, 1)

// Simple elementwise fp32->fp16 of W then u (8 elems/thread), layouts unchanged.
__global__ void cvt_kernel(const float* __restrict__ W, const float* __restrict__ u,
                           __half2* __restrict__ Wh, __half2* __restrict__ uh) {
    const int idx = blockIdx.x * blockDim.x + threadIdx.x;
    const int wg = W_ELEMS / 8;            // 184320
    const float4* p;
    __half2* o;
    if (idx < wg) {
        p = (const float4*)W + (size_t)idx * 2;
        o = Wh + (size_t)idx * 4;
    } else {
        const int j = idx - wg;            // < 294912
        p = (const float4*)u + (size_t)j * 2;
        o = uh + (size_t)j * 4;
    }
    const float4 a = p[0], b = p[1];
    o[0] = __floats2half2_rn(a.x, a.y);
    o[1] = __floats2half2_rn(a.z, a.w);
    o[2] = __floats2half2_rn(b.x, b.y);
    o[3] = __floats2half2_rn(b.z, b.w);
}

// One block per (b, k). Lane (oh = lane&1, pr = lane>>1) of wave w owns rows
// n = 192*rr + 32*w + pr (rr=0..5) and o in [8*oh, 8*oh+8) — u_hat in 24 VGPRs.
// Routing fully register/shfl-based; LDS = redS exchange only; 3 barriers.
// RULE-20 FIX vs round 9: v broadcast builds vo[4] (this lane's own oh-half)
// so every register-array subscript is compile-time static. No vh[4*oh+jj].
template<bool HALF>
__global__ __launch_bounds__(NT, 6)
void digitcaps_kernel(const float* __restrict__ u32, const float* __restrict__ W32,
                      const __half* __restrict__ uh, const __half* __restrict__ Wh,
                      float* __restrict__ out)
{
    const int t    = threadIdx.x;
    const int lane = t & 63;
    const int wav  = t >> 6;
    const int oh   = lane & 1;
    const int pr   = lane >> 1;          // 0..31
    const int b    = blockIdx.x;         // 0..255
    const int k    = blockIdx.y;         // 0..9

    __shared__ float redS[2][NW][20];    // [buf][wav][s0..15, d, m_w, pad2] = 960 B

    unsigned uh_r[6][4];                 // [rr][jj]: half2(uh[n][8oh+2jj], uh[n][8oh+2jj+1])

    // ---------------- Phase 1: u_hat = u . W (round-8 verified body -> regs) ----------------
    #pragma unroll
    for (int rr = 0; rr < 6; ++rr) {
        const int n = 192 * rr + 32 * wav + pr;
        float a0[8];
        #pragma unroll
        for (int o = 0; o < 8; ++o) a0[o] = 0.f;
        if (HALF) {
            const uint4 uq = *(const uint4*)(uh + ((size_t)b * Nn + n) * 8);
            const unsigned uw[4] = {uq.x, uq.y, uq.z, uq.w};
            const __half* wbase = Wh + ((size_t)(k * Nn + n)) * 128 + oh * 8;
            #pragma unroll
            for (int p = 0; p < 4; ++p) {
                const uint4 qa = *(const uint4*)(wbase + (2 * p    ) * 16);
                const uint4 qb = *(const uint4*)(wbase + (2 * p + 1) * 16);
                const unsigned aw[4] = {qa.x, qa.y, qa.z, qa.w};
                const unsigned bw[4] = {qb.x, qb.y, qb.z, qb.w};
                #pragma unroll
                for (int jj = 0; jj < 4; ++jj) {
                    const unsigned wl  = __builtin_amdgcn_perm(aw[jj], bw[jj], PERM_LO);
                    const unsigned wh2 = __builtin_amdgcn_perm(aw[jj], bw[jj], PERM_HI);
                    a0[2*jj]   = fdot2u(wl,  uw[p], a0[2*jj]);
                    a0[2*jj+1] = fdot2u(wh2, uw[p], a0[2*jj+1]);
                }
            }
        } else {
            float ua[8];
            const float4* up = (const float4*)(u32 + ((size_t)b * Nn + n) * 8);
            const float4 x0 = up[0], x1 = up[1];
            ua[0]=x0.x; ua[1]=x0.y; ua[2]=x0.z; ua[3]=x0.w;
            ua[4]=x1.x; ua[5]=x1.y; ua[6]=x1.z; ua[7]=x1.w;
            #pragma unroll
            for (int i = 0; i < 8; ++i) {
                const float4* wp = (const float4*)(W32 + ((size_t)k * Nn + n) * 128) + oh * 2 + i * 4;
                const float4 w0 = wp[0], w1 = wp[1];
                float wv[8];
                wv[0]=w0.x; wv[1]=w0.y; wv[2]=w0.z; wv[3]=w0.w;
                wv[4]=w1.x; wv[5]=w1.y; wv[6]=w1.z; wv[7]=w1.w;
                const float x = ua[i];
                #pragma unroll
                for (int o = 0; o < 8; ++o) a0[o] += x * wv[o];
            }
        }
        #pragma unroll
        for (int jj = 0; jj < 4; ++jj)
            uh_r[rr][jj] = pkh2(a0[2*jj], a0[2*jj+1]);
    }

    // ---------------- Phase 2: routing (register/shfl; 1 barrier per iter) ----------------
    float lg[6] = {0.f, 0.f, 0.f, 0.f, 0.f, 0.f};
    unsigned vo[4];                      // this lane's own oh-half of v, packed half2

    #pragma unroll
    for (int it = 0; it < 3; ++it) {
        float m_w = 0.f;
        float c[6];
        if (it > 0) {
            // ---- a-scan: own 8 o via dot2 (static vo[jj]), partner half via shfl_xor(1) ----
            #pragma unroll
            for (int rr = 0; rr < 6; ++rr) {
                float acc = 0.f;
                #pragma unroll
                for (int jj = 0; jj < 4; ++jj)
                    acc = fdot2u(uh_r[rr][jj], vo[jj], acc);
                lg[rr] += acc + __shfl_xor(acc, 1);
            }
            // ---- per-wave max (regs + shfl only) ----
            float m = lg[0];
            #pragma unroll
            for (int rr = 1; rr < 6; ++rr) m = fmaxf(m, lg[rr]);
            #pragma unroll
            for (int off = 1; off <= 32; off <<= 1)
                m = fmaxf(m, __shfl_xor(m, off));
            m_w = m;
            // ---- c in registers (e <= 1; oh pair computes identical values) ----
            #pragma unroll
            for (int rr = 0; rr < 6; ++rr) c[rr] = __expf(lg[rr] - m_w);
        } else {
            #pragma unroll
            for (int rr = 0; rr < 6; ++rr) c[rr] = 1.f;
        }

        // ---- s-scan: in-register row-pair perm + dot2 ----
        float sp[8] = {0.f, 0.f, 0.f, 0.f, 0.f, 0.f, 0.f, 0.f};
        float dp = 0.f;
        #pragma unroll
        for (int q = 0; q < 3; ++q) {
            const unsigned cp = pkh2(c[2*q], c[2*q+1]);    // (c[n_2q] lo, c[n_2q+1] hi)
            dp = fdot2u(cp, ONE2, dp);
            #pragma unroll
            for (int jj = 0; jj < 4; ++jj) {
                const unsigned px = __builtin_amdgcn_perm(uh_r[2*q][jj], uh_r[2*q+1][jj], PERM_LO);
                const unsigned py = __builtin_amdgcn_perm(uh_r[2*q][jj], uh_r[2*q+1][jj], PERM_HI);
                sp[2*jj]   = fdot2u(px, cp, sp[2*jj]);
                sp[2*jj+1] = fdot2u(py, cp, sp[2*jj+1]);
            }
        }
        // reduce over pr lanes; offsets 2..32 keep oh groups separate (no d double-count)
        #pragma unroll
        for (int off = 2; off <= 32; off <<= 1) {
            #pragma unroll
            for (int e = 0; e < 8; ++e) sp[e] += __shfl_xor(sp[e], off);
            dp += __shfl_xor(dp, off);
        }
        const int buf = it & 1;
        if (lane < 2) {      // lane == oh here; lane0 -> s[0..7], lane1 -> s[8..15]
            float2* dst = (float2*)&redS[buf][wav][8 * lane];
            dst[0] = make_float2(sp[0], sp[1]);
            dst[1] = make_float2(sp[2], sp[3]);
            dst[2] = make_float2(sp[4], sp[5]);
            dst[3] = make_float2(sp[6], sp[7]);
        }
        if (lane == 0)
            *(float2*)&redS[buf][wav][16] = make_float2(dp, m_w);
        __syncthreads();                               // the ONLY barrier per iter

        // ---- finalize: cross-wave rescale + squash (round-8 verified) ----
        if (it < 2 || wav == 0) {
            const int o = lane & 15;
            float M = redS[buf][0][17];
            #pragma unroll
            for (int w = 1; w < NW; ++w) M = fmaxf(M, redS[buf][w][17]);
            float s = 0.f, d = 0.f;
            #pragma unroll
            for (int w = 0; w < NW; ++w) {
                const float2 dm = *(const float2*)&redS[buf][w][16];
                const float sc = (it == 0) ? 1.f : __expf(dm.y - M);
                s += sc * redS[buf][w][o];
                d += sc * dm.x;
            }
            s /= d;
            float s2 = s * s;
            #pragma unroll
            for (int off = 1; off <= 8; off <<= 1) s2 += __shfl_xor(s2, off);
            const float scale = (s2 / (1.f + s2)) * rsqrtf(fmaxf(s2, 1e-30f));
            const float v = s * scale;
            if (it == 2) {
                if (wav == 0 && lane < 16)
                    out[((size_t)k * Bsz + b) * 16 + lane] = v;
            } else {
                // build THIS lane's oh-half: v[8*oh + 2*jj], v[8*oh + 2*jj + 1].
                // runtime shfl *lane index* is fine; array subscript jj is static.
                #pragma unroll
                for (int jj = 0; jj < 4; ++jj)
                    vo[jj] = pkh2(__shfl(v, 8 * oh + 2 * jj),
                                  __shfl(v, 8 * oh + 2 * jj + 1));
            }
        }
    }
}

extern "C" void kernel_launch(void* const* d_in, const int* in_sizes, int n_in,
                              void* d_out, int out_size, void* d_ws, size_t ws_size,
                              hipStream_t stream) {
    const float* u = (const float*)d_in[0];
    const float* W = (const float*)d_in[1];
    float* out = (float*)d_out;
    const size_t need = (size_t)(W_ELEMS + U_ELEMS) * sizeof(__half);
    if (ws_size >= need) {
        __half* Wh = (__half*)d_ws;
        __half* uh = (__half*)((char*)d_ws + (size_t)W_ELEMS * sizeof(__half));
        cvt_kernel<<<dim3((W_ELEMS + U_ELEMS) / 8 / 256), dim3(256), 0, stream>>>(
            W, u, (__half2*)Wh, (__half2*)uh);
        digitcaps_kernel<true><<<dim3(256, 10), dim3(NT), 0, stream>>>(
            nullptr, nullptr, uh, Wh, out);
    } else {
        digitcaps_kernel<false><<<dim3(256, 10), dim3(NT), 0, stream>>>(
            u, W, nullptr, nullptr, out);
    }
}

// Round 12
// 137.237 us; speedup vs baseline: 1.1917x; 1.0605x over previous
//
#include <hip/hip_runtime.h>
#include <hip/hip_fp16.h>

#define Bsz 256
#define Nn  1152
#define Kk  10
#define NT  384      // 6 waves/block
#define NW  6

#define W_ELEMS (Kk*Nn*128)     // 1474560
#define U_ELEMS (Bsz*Nn*8)      // 2359296

typedef _Float16 hf2_t __attribute__((ext_vector_type(2)));

static __device__ __forceinline__ unsigned pkh2(float x, float y) {
    __half2 h = __floats2half2_rn(x, y);
    return *reinterpret_cast<unsigned*>(&h);
}
// v_dot2_f32_f16: c += a.lo*b.lo + a.hi*b.hi (f32 accumulate, 1 inst)
static __device__ __forceinline__ float fdot2u(unsigned a, unsigned b, float c) {
    union { unsigned u; hf2_t h; } A, B;
    A.u = a; B.u = b;
    return __builtin_amdgcn_fdot2(A.h, B.h, c, false);
}

#define PERM_LO 0x01000504u   // perm(a,b,LO) = half2(lo = lo16(a), hi = lo16(b))
#define PERM_HI 0x03020706u   // perm(a,b,HI) = half2(lo = hi16(a), hi = hi16(b))
#define ONE2    0x3C003C00u   // half2(1, 1)

// Simple elementwise fp32->fp16 of W then u (8 elems/thread), layouts unchanged.
__global__ void cvt_kernel(const float* __restrict__ W, const float* __restrict__ u,
                           __half2* __restrict__ Wh, __half2* __restrict__ uh) {
    const int idx = blockIdx.x * blockDim.x + threadIdx.x;
    const int wg = W_ELEMS / 8;            // 184320
    const float4* p;
    __half2* o;
    if (idx < wg) {
        p = (const float4*)W + (size_t)idx * 2;
        o = Wh + (size_t)idx * 4;
    } else {
        const int j = idx - wg;            // < 294912
        p = (const float4*)u + (size_t)j * 2;
        o = uh + (size_t)j * 4;
    }
    const float4 a = p[0], b = p[1];
    o[0] = __floats2half2_rn(a.x, a.y);
    o[1] = __floats2half2_rn(a.z, a.w);
    o[2] = __floats2half2_rn(b.x, b.y);
    o[3] = __floats2half2_rn(b.z, b.w);
}

// One block per (b, k). Lane (oh = lane&1, pr = lane>>1) of wave w owns rows
// n = 192*rr + 32*w + pr (rr=0..5) and o in [8*oh, 8*oh+8) — u_hat in 24 VGPRs.
// Routing fully register/shfl-based; LDS = redS exchange only; 3 barriers.
// ROUND-12 FIX: __launch_bounds__(384, 4) — the (384,6) promise capped the
// allocator at ~84 VGPRs and spilled ~11 regs (42 MB scratch writes, round 11).
// 128-reg cap fits the ~110 live regs spill-free; occupancy was exonerated in
// round 2, so trading 24 -> 16 waves/CU costs nothing.
template<bool HALF>
__global__ __launch_bounds__(NT, 4)
void digitcaps_kernel(const float* __restrict__ u32, const float* __restrict__ W32,
                      const __half* __restrict__ uh, const __half* __restrict__ Wh,
                      float* __restrict__ out)
{
    const int t    = threadIdx.x;
    const int lane = t & 63;
    const int wav  = t >> 6;
    const int oh   = lane & 1;
    const int pr   = lane >> 1;          // 0..31
    const int b    = blockIdx.x;         // 0..255
    const int k    = blockIdx.y;         // 0..9

    __shared__ float redS[2][NW][20];    // [buf][wav][s0..15, d, m_w, pad2] = 960 B

    unsigned uh_r[6][4];                 // [rr][jj]: half2(uh[n][8oh+2jj], uh[n][8oh+2jj+1])

    // ---------------- Phase 1: u_hat = u . W (round-8 verified body -> regs) ----------------
    #pragma unroll
    for (int rr = 0; rr < 6; ++rr) {
        const int n = 192 * rr + 32 * wav + pr;
        float a0[8];
        #pragma unroll
        for (int o = 0; o < 8; ++o) a0[o] = 0.f;
        if (HALF) {
            const uint4 uq = *(const uint4*)(uh + ((size_t)b * Nn + n) * 8);
            const unsigned uw[4] = {uq.x, uq.y, uq.z, uq.w};
            const __half* wbase = Wh + ((size_t)(k * Nn + n)) * 128 + oh * 8;
            #pragma unroll
            for (int p = 0; p < 4; ++p) {
                const uint4 qa = *(const uint4*)(wbase + (2 * p    ) * 16);
                const uint4 qb = *(const uint4*)(wbase + (2 * p + 1) * 16);
                const unsigned aw[4] = {qa.x, qa.y, qa.z, qa.w};
                const unsigned bw[4] = {qb.x, qb.y, qb.z, qb.w};
                #pragma unroll
                for (int jj = 0; jj < 4; ++jj) {
                    const unsigned wl  = __builtin_amdgcn_perm(aw[jj], bw[jj], PERM_LO);
                    const unsigned wh2 = __builtin_amdgcn_perm(aw[jj], bw[jj], PERM_HI);
                    a0[2*jj]   = fdot2u(wl,  uw[p], a0[2*jj]);
                    a0[2*jj+1] = fdot2u(wh2, uw[p], a0[2*jj+1]);
                }
            }
        } else {
            float ua[8];
            const float4* up = (const float4*)(u32 + ((size_t)b * Nn + n) * 8);
            const float4 x0 = up[0], x1 = up[1];
            ua[0]=x0.x; ua[1]=x0.y; ua[2]=x0.z; ua[3]=x0.w;
            ua[4]=x1.x; ua[5]=x1.y; ua[6]=x1.z; ua[7]=x1.w;
            #pragma unroll
            for (int i = 0; i < 8; ++i) {
                const float4* wp = (const float4*)(W32 + ((size_t)k * Nn + n) * 128) + oh * 2 + i * 4;
                const float4 w0 = wp[0], w1 = wp[1];
                float wv[8];
                wv[0]=w0.x; wv[1]=w0.y; wv[2]=w0.z; wv[3]=w0.w;
                wv[4]=w1.x; wv[5]=w1.y; wv[6]=w1.z; wv[7]=w1.w;
                const float x = ua[i];
                #pragma unroll
                for (int o = 0; o < 8; ++o) a0[o] += x * wv[o];
            }
        }
        #pragma unroll
        for (int jj = 0; jj < 4; ++jj)
            uh_r[rr][jj] = pkh2(a0[2*jj], a0[2*jj+1]);
    }

    // ---------------- Phase 2: routing (register/shfl; 1 barrier per iter) ----------------
    float lg[6] = {0.f, 0.f, 0.f, 0.f, 0.f, 0.f};
    unsigned vo[4];                      // this lane's own oh-half of v, packed half2

    #pragma unroll
    for (int it = 0; it < 3; ++it) {
        float m_w = 0.f;
        float c[6];
        if (it > 0) {
            // ---- a-scan: own 8 o via dot2 (static vo[jj]), partner half via shfl_xor(1) ----
            #pragma unroll
            for (int rr = 0; rr < 6; ++rr) {
                float acc = 0.f;
                #pragma unroll
                for (int jj = 0; jj < 4; ++jj)
                    acc = fdot2u(uh_r[rr][jj], vo[jj], acc);
                lg[rr] += acc + __shfl_xor(acc, 1);
            }
            // ---- per-wave max (regs + shfl only) ----
            float m = lg[0];
            #pragma unroll
            for (int rr = 1; rr < 6; ++rr) m = fmaxf(m, lg[rr]);
            #pragma unroll
            for (int off = 1; off <= 32; off <<= 1)
                m = fmaxf(m, __shfl_xor(m, off));
            m_w = m;
            // ---- c in registers (e <= 1; oh pair computes identical values) ----
            #pragma unroll
            for (int rr = 0; rr < 6; ++rr) c[rr] = __expf(lg[rr] - m_w);
        } else {
            #pragma unroll
            for (int rr = 0; rr < 6; ++rr) c[rr] = 1.f;
        }

        // ---- s-scan: in-register row-pair perm + dot2 ----
        float sp[8] = {0.f, 0.f, 0.f, 0.f, 0.f, 0.f, 0.f, 0.f};
        float dp = 0.f;
        #pragma unroll
        for (int q = 0; q < 3; ++q) {
            const unsigned cp = pkh2(c[2*q], c[2*q+1]);    // (c[n_2q] lo, c[n_2q+1] hi)
            dp = fdot2u(cp, ONE2, dp);
            #pragma unroll
            for (int jj = 0; jj < 4; ++jj) {
                const unsigned px = __builtin_amdgcn_perm(uh_r[2*q][jj], uh_r[2*q+1][jj], PERM_LO);
                const unsigned py = __builtin_amdgcn_perm(uh_r[2*q][jj], uh_r[2*q+1][jj], PERM_HI);
                sp[2*jj]   = fdot2u(px, cp, sp[2*jj]);
                sp[2*jj+1] = fdot2u(py, cp, sp[2*jj+1]);
            }
        }
        // reduce over pr lanes; offsets 2..32 keep oh groups separate (no d double-count)
        #pragma unroll
        for (int off = 2; off <= 32; off <<= 1) {
            #pragma unroll
            for (int e = 0; e < 8; ++e) sp[e] += __shfl_xor(sp[e], off);
            dp += __shfl_xor(dp, off);
        }
        const int buf = it & 1;
        if (lane < 2) {      // lane == oh here; lane0 -> s[0..7], lane1 -> s[8..15]
            float2* dst = (float2*)&redS[buf][wav][8 * lane];
            dst[0] = make_float2(sp[0], sp[1]);
            dst[1] = make_float2(sp[2], sp[3]);
            dst[2] = make_float2(sp[4], sp[5]);
            dst[3] = make_float2(sp[6], sp[7]);
        }
        if (lane == 0)
            *(float2*)&redS[buf][wav][16] = make_float2(dp, m_w);
        __syncthreads();                               // the ONLY barrier per iter

        // ---- finalize: cross-wave rescale + squash (round-8 verified) ----
        if (it < 2 || wav == 0) {
            const int o = lane & 15;
            float M = redS[buf][0][17];
            #pragma unroll
            for (int w = 1; w < NW; ++w) M = fmaxf(M, redS[buf][w][17]);
            float s = 0.f, d = 0.f;
            #pragma unroll
            for (int w = 0; w < NW; ++w) {
                const float2 dm = *(const float2*)&redS[buf][w][16];
                const float sc = (it == 0) ? 1.f : __expf(dm.y - M);
                s += sc * redS[buf][w][o];
                d += sc * dm.x;
            }
            s /= d;
            float s2 = s * s;
            #pragma unroll
            for (int off = 1; off <= 8; off <<= 1) s2 += __shfl_xor(s2, off);
            const float scale = (s2 / (1.f + s2)) * rsqrtf(fmaxf(s2, 1e-30f));
            const float v = s * scale;
            if (it == 2) {
                if (wav == 0 && lane < 16)
                    out[((size_t)k * Bsz + b) * 16 + lane] = v;
            } else {
                // build THIS lane's oh-half: v[8*oh + 2*jj], v[8*oh + 2*jj + 1].
                // runtime shfl *lane index* is fine; array subscript jj is static.
                #pragma unroll
                for (int jj = 0; jj < 4; ++jj)
                    vo[jj] = pkh2(__shfl(v, 8 * oh + 2 * jj),
                                  __shfl(v, 8 * oh + 2 * jj + 1));
            }
        }
    }
}

extern "C" void kernel_launch(void* const* d_in, const int* in_sizes, int n_in,
                              void* d_out, int out_size, void* d_ws, size_t ws_size,
                              hipStream_t stream) {
    const float* u = (const float*)d_in[0];
    const float* W = (const float*)d_in[1];
    float* out = (float*)d_out;
    const size_t need = (size_t)(W_ELEMS + U_ELEMS) * sizeof(__half);
    if (ws_size >= need) {
        __half* Wh = (__half*)d_ws;
        __half* uh = (__half*)((char*)d_ws + (size_t)W_ELEMS * sizeof(__half));
        cvt_kernel<<<dim3((W_ELEMS + U_ELEMS) / 8 / 256), dim3(256), 0, stream>>>(
            W, u, (__half2*)Wh, (__half2*)uh);
        digitcaps_kernel<true><<<dim3(256, 10), dim3(NT), 0, stream>>>(
            nullptr, nullptr, uh, Wh, out);
    } else {
        digitcaps_kernel<false><<<dim3(256, 10), dim3(NT), 0, stream>>>(
            u, W, nullptr, nullptr, out);
    }
}

// Round 13
// 121.445 us; speedup vs baseline: 1.3467x; 1.1300x over previous
//
#include <hip/hip_runtime.h>
#include <hip/hip_fp16.h>

#define Bsz 256
#define Nn  1152
#define Kk  10
#define NT  384      // 6 waves/block
#define NW  6
#define S4  1156     // uint stride per o-pair row (R8-verified layout)

#define W_ELEMS (Kk*Nn*128)     // 1474560
#define U_ELEMS (Bsz*Nn*8)      // 2359296

typedef _Float16 hf2_t __attribute__((ext_vector_type(2)));

static __device__ __forceinline__ unsigned pkh2(float x, float y) {
    __half2 h = __floats2half2_rn(x, y);
    return *reinterpret_cast<unsigned*>(&h);
}
// v_dot2_f32_f16: c += a.lo*b.lo + a.hi*b.hi (f32 accumulate, 1 inst)
static __device__ __forceinline__ float fdot2u(unsigned a, unsigned b, float c) {
    union { unsigned u; hf2_t h; } A, B;
    A.u = a; B.u = b;
    return __builtin_amdgcn_fdot2(A.h, B.h, c, false);
}
// Within-wave LDS write->read ordering (no s_barrier for wave-local data)
static __device__ __forceinline__ void wave_lds_fence() {
    __builtin_amdgcn_sched_barrier(0);
    asm volatile("s_waitcnt lgkmcnt(0)" ::: "memory");
    __builtin_amdgcn_sched_barrier(0);
}

#define PERM_LO 0x01000504u   // perm(a,b,LO) = half2(lo = lo16(a), hi = lo16(b))
#define PERM_HI 0x03020706u
#define ONE2    0x3C003C00u   // half2(1, 1)

// Simple elementwise fp32->fp16 of W then u (8 elems/thread), layouts unchanged.
__global__ void cvt_kernel(const float* __restrict__ W, const float* __restrict__ u,
                           __half2* __restrict__ Wh, __half2* __restrict__ uh) {
    const int idx = blockIdx.x * blockDim.x + threadIdx.x;
    const int wg = W_ELEMS / 8;            // 184320
    const float4* p;
    __half2* o;
    if (idx < wg) {
        p = (const float4*)W + (size_t)idx * 2;
        o = Wh + (size_t)idx * 4;
    } else {
        const int j = idx - wg;            // < 294912
        p = (const float4*)u + (size_t)j * 2;
        o = uh + (size_t)j * 4;
    }
    const float4 a = p[0], b = p[1];
    o[0] = __floats2half2_rn(a.x, a.y);
    o[1] = __floats2half2_rn(a.z, a.w);
    o[2] = __floats2half2_rn(b.x, b.y);
    o[3] = __floats2half2_rn(b.z, b.w);
}

// One block per (b-pair, k): b0 = 2*bg (u_hat in LDS, R8 routing), b1 = 2*bg+1
// (u_hat in 24 regs, R12 routing). Phase 1 loads each W cell ONCE for both b's
// -> W L2 stream halves. Per-wave softmax per b; cross-wave exp(m_w - M) rescale
// at finalize (b = (lane>>4)&1). 3 barriers + wave-local fences.
// VGPR target ~100 under __launch_bounds__(384,4)=128 cap — if WRITE_SIZE
// balloons, it spilled (rounds 6/7/9/11 lesson).
template<bool HALF>
__global__ __launch_bounds__(NT, 4)
void digitcaps_kernel(const float* __restrict__ u32, const float* __restrict__ W32,
                      const __half* __restrict__ uh, const __half* __restrict__ Wh,
                      float* __restrict__ out)
{
    const int t    = threadIdx.x;
    const int lane = t & 63;
    const int wav  = t >> 6;
    const int oh   = lane & 1;
    const int pr   = lane >> 1;          // 0..31
    const int bg   = blockIdx.x;         // 0..127
    const int k    = blockIdx.y;         // 0..9
    const int b0   = 2 * bg;
    const int b1   = 2 * bg + 1;

    __shared__ unsigned uhS[8 * S4];        // 36992 B  b0 u_hat: row j = o-pair, col n
    __shared__ unsigned cS2u[Nn / 2];       // 2304 B   b0 e per n (half), uint-paired
    __shared__ float    redS[2][2][NW][20]; // 1920 B   [buf][b][wav][s0..15, d, m_w, pad2]
    // total 41216 B -> 3 blocks/CU (LDS); VGPR ~100 -> ~5 waves/SIMD: 18 waves/CU

    unsigned uh_r[6][4];    // b1 u_hat: [rr][jj] = half2(o=8oh+2jj, +1) for n=192rr+32wav+pr

    // ---------------- Phase 1: u_hat = u . W for BOTH b's, W loaded once ----------------
    #pragma unroll
    for (int rr = 0; rr < 6; ++rr) {
        const int n = 192 * rr + 32 * wav + pr;
        float a0[8], a1[8];
        #pragma unroll
        for (int o = 0; o < 8; ++o) { a0[o] = 0.f; a1[o] = 0.f; }
        if (HALF) {
            const uint4 uq0 = *(const uint4*)(uh + ((size_t)b0 * Nn + n) * 8);
            const uint4 uq1 = *(const uint4*)(uh + ((size_t)b1 * Nn + n) * 8);
            const unsigned uw0[4] = {uq0.x, uq0.y, uq0.z, uq0.w};
            const unsigned uw1[4] = {uq1.x, uq1.y, uq1.z, uq1.w};
            const __half* wbase = Wh + ((size_t)(k * Nn + n)) * 128 + oh * 8;
            #pragma unroll
            for (int p = 0; p < 4; ++p) {
                const uint4 qa = *(const uint4*)(wbase + (2 * p    ) * 16);
                const uint4 qb = *(const uint4*)(wbase + (2 * p + 1) * 16);
                const unsigned aw[4] = {qa.x, qa.y, qa.z, qa.w};
                const unsigned bw[4] = {qb.x, qb.y, qb.z, qb.w};
                #pragma unroll
                for (int jj = 0; jj < 4; ++jj) {
                    const unsigned wl  = __builtin_amdgcn_perm(aw[jj], bw[jj], PERM_LO);
                    const unsigned wh2 = __builtin_amdgcn_perm(aw[jj], bw[jj], PERM_HI);
                    a0[2*jj]   = fdot2u(wl,  uw0[p], a0[2*jj]);
                    a0[2*jj+1] = fdot2u(wh2, uw0[p], a0[2*jj+1]);
                    a1[2*jj]   = fdot2u(wl,  uw1[p], a1[2*jj]);
                    a1[2*jj+1] = fdot2u(wh2, uw1[p], a1[2*jj+1]);
                }
            }
        } else {
            float ua0[8], ua1[8];
            const float4* up0 = (const float4*)(u32 + ((size_t)b0 * Nn + n) * 8);
            const float4* up1 = (const float4*)(u32 + ((size_t)b1 * Nn + n) * 8);
            const float4 x0 = up0[0], x1 = up0[1];
            const float4 y0 = up1[0], y1 = up1[1];
            ua0[0]=x0.x; ua0[1]=x0.y; ua0[2]=x0.z; ua0[3]=x0.w;
            ua0[4]=x1.x; ua0[5]=x1.y; ua0[6]=x1.z; ua0[7]=x1.w;
            ua1[0]=y0.x; ua1[1]=y0.y; ua1[2]=y0.z; ua1[3]=y0.w;
            ua1[4]=y1.x; ua1[5]=y1.y; ua1[6]=y1.z; ua1[7]=y1.w;
            #pragma unroll
            for (int i = 0; i < 8; ++i) {
                const float4* wp = (const float4*)(W32 + ((size_t)k * Nn + n) * 128) + oh * 2 + i * 4;
                const float4 w0 = wp[0], w1 = wp[1];
                float wv[8];
                wv[0]=w0.x; wv[1]=w0.y; wv[2]=w0.z; wv[3]=w0.w;
                wv[4]=w1.x; wv[5]=w1.y; wv[6]=w1.z; wv[7]=w1.w;
                const float x = ua0[i], y = ua1[i];
                #pragma unroll
                for (int o = 0; o < 8; ++o) { a0[o] += x * wv[o]; a1[o] += y * wv[o]; }
            }
        }
        #pragma unroll
        for (int jj = 0; jj < 4; ++jj) {
            uhS[(oh * 4 + jj) * S4 + n] = pkh2(a0[2*jj], a0[2*jj+1]);
            uh_r[rr][jj] = pkh2(a1[2*jj], a1[2*jj+1]);
        }
    }
    wave_lds_fence();   // all later uhS/cS consumption is wave-local

    // ---------------- Phase 2: routing ----------------
    float lg0[3] = {0.f, 0.f, 0.f};                         // b0 (LDS rows)
    float lg1[6] = {0.f, 0.f, 0.f, 0.f, 0.f, 0.f};          // b1 (reg rows)
    unsigned vh0[8];    // full v_b0 (b0 a-scan reads all 16 o from LDS)
    unsigned vo1[4];    // own oh-half of v_b1
    const int j_s = lane & 7;
    const int g_s = lane >> 3;
    const int l5  = lane >> 5;
    const int l31 = lane & 31;

    #pragma unroll
    for (int it = 0; it < 3; ++it) {
        float m0 = 0.f, m1 = 0.f;
        float c1[6];
        if (it > 0) {
            // ---- b0 a-scan (R8): own LDS columns n = 384j + 192 l5 + 32 wav + l31 ----
            #pragma unroll
            for (int j = 0; j < 3; ++j) {
                const int n = 384 * j + 192 * l5 + 32 * wav + l31;
                float acc = 0.f;
                #pragma unroll
                for (int jj = 0; jj < 8; ++jj)
                    acc = fdot2u(uhS[jj * S4 + n], vh0[jj], acc);
                lg0[j] += acc;
            }
            // ---- b1 a-scan (R12): own regs + oh-partner shfl ----
            #pragma unroll
            for (int rr = 0; rr < 6; ++rr) {
                float acc = 0.f;
                #pragma unroll
                for (int jj = 0; jj < 4; ++jj)
                    acc = fdot2u(uh_r[rr][jj], vo1[jj], acc);
                lg1[rr] += acc + __shfl_xor(acc, 1);
            }
            // ---- per-wave maxes ----
            m0 = fmaxf(fmaxf(lg0[0], lg0[1]), lg0[2]);
            m1 = fmaxf(fmaxf(fmaxf(lg1[0], lg1[1]), fmaxf(lg1[2], lg1[3])),
                       fmaxf(lg1[4], lg1[5]));
            #pragma unroll
            for (int off = 1; off <= 32; off <<= 1) {
                m0 = fmaxf(m0, __shfl_xor(m0, off));
                m1 = fmaxf(m1, __shfl_xor(m1, off));
            }
            // ---- b0 e -> LDS (half per n); b1 c -> regs ----
            #pragma unroll
            for (int j = 0; j < 3; ++j) {
                const int n = 384 * j + 192 * l5 + 32 * wav + l31;
                ((__half*)cS2u)[n] = __float2half(__expf(lg0[j] - m0));
            }
            #pragma unroll
            for (int rr = 0; rr < 6; ++rr) c1[rr] = __expf(lg1[rr] - m1);
            wave_lds_fence();   // cS readers are this same wave
        } else {
            #pragma unroll
            for (int rr = 0; rr < 6; ++rr) c1[rr] = 1.f;
        }

        // ---- b0 s-scan (R8): LDS pairs (n0, n0+1) ----
        float2 sp0 = {0.f, 0.f};
        float dp0 = 0.f;
        #pragma unroll
        for (int cc = 0; cc < 12; ++cc) {
            const int P  = g_s + 8 * cc;
            const int n0 = 192 * (P >> 4) + 32 * wav + 2 * (P & 15);
            const unsigned cp = (it == 0) ? ONE2 : cS2u[n0 >> 1];
            const uint2 q = *(const uint2*)&uhS[j_s * S4 + n0];
            const unsigned px = __builtin_amdgcn_perm(q.x, q.y, PERM_LO);
            const unsigned py = __builtin_amdgcn_perm(q.x, q.y, PERM_HI);
            sp0.x = fdot2u(px, cp, sp0.x);
            sp0.y = fdot2u(py, cp, sp0.y);
            dp0   = fdot2u(cp, ONE2, dp0);
        }
        #pragma unroll
        for (int off = 8; off <= 32; off <<= 1) {
            sp0.x += __shfl_xor(sp0.x, off);
            sp0.y += __shfl_xor(sp0.y, off);
            dp0   += __shfl_xor(dp0,   off);
        }

        // ---- b1 s-scan (R12): in-register row-pair perm + dot2 ----
        float sp1[8] = {0.f, 0.f, 0.f, 0.f, 0.f, 0.f, 0.f, 0.f};
        float dp1 = 0.f;
        #pragma unroll
        for (int q2 = 0; q2 < 3; ++q2) {
            const unsigned cp1 = pkh2(c1[2*q2], c1[2*q2+1]);
            dp1 = fdot2u(cp1, ONE2, dp1);
            #pragma unroll
            for (int jj = 0; jj < 4; ++jj) {
                const unsigned px = __builtin_amdgcn_perm(uh_r[2*q2][jj], uh_r[2*q2+1][jj], PERM_LO);
                const unsigned py = __builtin_amdgcn_perm(uh_r[2*q2][jj], uh_r[2*q2+1][jj], PERM_HI);
                sp1[2*jj]   = fdot2u(px, cp1, sp1[2*jj]);
                sp1[2*jj+1] = fdot2u(py, cp1, sp1[2*jj+1]);
            }
        }
        #pragma unroll
        for (int off = 2; off <= 32; off <<= 1) {     // keep oh groups separate
            #pragma unroll
            for (int e = 0; e < 8; ++e) sp1[e] += __shfl_xor(sp1[e], off);
            dp1 += __shfl_xor(dp1, off);
        }

        const int buf = it & 1;
        if (lane < 8) {
            redS[buf][0][wav][2 * j_s    ] = sp0.x;
            redS[buf][0][wav][2 * j_s + 1] = sp0.y;
        }
        if (lane < 2) {      // lane == oh; lane0 -> s[0..7], lane1 -> s[8..15]
            float2* dst = (float2*)&redS[buf][1][wav][8 * lane];
            dst[0] = make_float2(sp1[0], sp1[1]);
            dst[1] = make_float2(sp1[2], sp1[3]);
            dst[2] = make_float2(sp1[4], sp1[5]);
            dst[3] = make_float2(sp1[6], sp1[7]);
        }
        if (lane == 0) {
            *(float2*)&redS[buf][0][wav][16] = make_float2(dp0, m0);
            *(float2*)&redS[buf][1][wav][16] = make_float2(dp1, m1);
        }
        __syncthreads();                               // the ONLY barrier per iter

        // ---- finalize: per-b cross-wave rescale + squash; b = (lane>>4)&1 ----
        if (it < 2 || wav == 0) {
            const int bsel = (lane >> 4) & 1;
            const int o    = lane & 15;
            float M = redS[buf][bsel][0][17];
            #pragma unroll
            for (int w = 1; w < NW; ++w) M = fmaxf(M, redS[buf][bsel][w][17]);
            float s = 0.f, d = 0.f;
            #pragma unroll
            for (int w = 0; w < NW; ++w) {
                const float2 dm = *(const float2*)&redS[buf][bsel][w][16];
                const float sc = (it == 0) ? 1.f : __expf(dm.y - M);
                s += sc * redS[buf][bsel][w][o];
                d += sc * dm.x;
            }
            s /= d;
            float s2 = s * s;
            #pragma unroll
            for (int off = 1; off <= 8; off <<= 1) s2 += __shfl_xor(s2, off);
            const float scale = (s2 / (1.f + s2)) * rsqrtf(fmaxf(s2, 1e-30f));
            const float v = s * scale;
            if (it == 2) {
                if (wav == 0 && lane < 32)
                    out[((size_t)k * Bsz + b0 + bsel) * 16 + o] = v;
            } else {
                // v_b0 lives in lanes 0-15, v_b1 in lanes 16-31 (static subscripts only)
                #pragma unroll
                for (int jj = 0; jj < 8; ++jj)
                    vh0[jj] = pkh2(__shfl(v, 2 * jj), __shfl(v, 2 * jj + 1));
                #pragma unroll
                for (int jj = 0; jj < 4; ++jj)
                    vo1[jj] = pkh2(__shfl(v, 16 + 8 * oh + 2 * jj),
                                   __shfl(v, 16 + 8 * oh + 2 * jj + 1));
            }
        }
    }
}

extern "C" void kernel_launch(void* const* d_in, const int* in_sizes, int n_in,
                              void* d_out, int out_size, void* d_ws, size_t ws_size,
                              hipStream_t stream) {
    const float* u = (const float*)d_in[0];
    const float* W = (const float*)d_in[1];
    float* out = (float*)d_out;
    const size_t need = (size_t)(W_ELEMS + U_ELEMS) * sizeof(__half);
    if (ws_size >= need) {
        __half* Wh = (__half*)d_ws;
        __half* uh = (__half*)((char*)d_ws + (size_t)W_ELEMS * sizeof(__half));
        cvt_kernel<<<dim3((W_ELEMS + U_ELEMS) / 8 / 256), dim3(256), 0, stream>>>(
            W, u, (__half2*)Wh, (__half2*)uh);
        digitcaps_kernel<true><<<dim3(128, 10), dim3(NT), 0, stream>>>(
            nullptr, nullptr, uh, Wh, out);
    } else {
        digitcaps_kernel<false><<<dim3(128, 10), dim3(NT), 0, stream>>>(
            u, W, nullptr, nullptr, out);
    }
}